// Round 1
// 948.208 us; speedup vs baseline: 4.8462x; 4.8462x over previous
//
#include <hip/hip_runtime.h>

// ---- problem constants ----
#define NB    8
#define HIN   384
#define WIN   384
#define HOUT  192
#define WOUT  192
#define HW_IN (HIN * WIN)          // 147456
#define PLANE (HOUT * WOUT)        // 36864
#define CNT_BN (NB * HOUT * WOUT)  // 294912

// ---- workspace layout (float offsets) ----
#define WS_MEANS 0       // 512:   per-(n,c) spatial means, n*64+c
#define WS_AGGV  512     // 24576: aggregated vert weights [n][c][t][o]
#define WS_AGGH  25088   // 24576: aggregated horz weights [n][c][t][o]
#define WS_SQW   49664   // 36864: sq weights transposed [c][ky][kx][oc]
#define WS_STATS 86528   // 128:   sum_v[32] sumsq_v[32] sum_h[32] sumsq_h[32]
#define WS_BN    86656   // 128:   scale_v[32] shift_v[32] scale_h[32] shift_h[32]

// ---------------- stats zero ----------------
__global__ void k_zero(float* __restrict__ ws) {
    if (threadIdx.x < 128) ws[WS_STATS + threadIdx.x] = 0.f;
}

// ---------------- per-(n,c) spatial mean ----------------
__global__ __launch_bounds__(256) void k_means(const float* __restrict__ x,
                                               float* __restrict__ ws) {
    int bc = blockIdx.x;  // n*64 + c, 512 blocks
    const float4* p = (const float4*)(x + (size_t)bc * HW_IN);
    float s = 0.f;
    for (int i = threadIdx.x; i < HW_IN / 4; i += 256) {
        float4 v = p[i];
        s += (v.x + v.y) + (v.z + v.w);
    }
    __shared__ float red[256];
    red[threadIdx.x] = s;
    __syncthreads();
    for (int off = 128; off > 0; off >>= 1) {
        if ((int)threadIdx.x < off) red[threadIdx.x] += red[threadIdx.x + off];
        __syncthreads();
    }
    if (threadIdx.x == 0) ws[WS_MEANS + bc] = red[0] * (1.0f / HW_IN);
}

// ---------------- attention + expert aggregation ----------------
__global__ void k_agg(const float* __restrict__ aw_v, const float* __restrict__ ab_v,
                      const float* __restrict__ wv,
                      const float* __restrict__ aw_h, const float* __restrict__ ab_h,
                      const float* __restrict__ wh, float* __restrict__ ws) {
    int n = blockIdx.x;  // 8 blocks
    __shared__ float att[8];  // [0..3] vert, [4..7] horz
    if (threadIdx.x < 8) {
        int k = threadIdx.x & 3;
        int hsel = threadIdx.x >> 2;
        const float* m = ws + WS_MEANS + n * 64 + hsel * 32;
        const float* aw = hsel ? aw_h : aw_v;
        const float* ab = hsel ? ab_h : ab_v;
        float z = ab[k];
        for (int c = 0; c < 32; c++) z += m[c] * aw[k * 32 + c];
        att[threadIdx.x] = 1.0f / (1.0f + expf(-z));
    }
    __syncthreads();
    // dst [c][t][o]: i = (c*3+t)*32 + o ; src [k][o][c][t] = (k*32+o)*96 + (c*3+t)
    for (int i = threadIdx.x; i < 3072; i += 256) {
        int o = i & 31;
        int r = i >> 5;  // c*3 + t
        float sv = 0.f, sh = 0.f;
#pragma unroll
        for (int k = 0; k < 4; k++) {
            sv += att[k]     * wv[(k * 32 + o) * 96 + r];
            sh += att[4 + k] * wh[(k * 32 + o) * 96 + r];
        }
        ws[WS_AGGV + n * 3072 + i] = sv;
        ws[WS_AGGH + n * 3072 + i] = sh;
    }
}

// ---------------- sq weight transpose: [oc][c][ky][kx] -> [c][ky][kx][oc] ----------------
__global__ void k_cvtw(const float* __restrict__ sq_w, float* __restrict__ ws) {
    int i = blockIdx.x * 256 + threadIdx.x;  // 36864 total, grid 144
    int oc = i & 63;
    int r = i >> 6;           // c*9 + (ky*3+kx)
    int c = r / 9, q = r % 9;
    ws[WS_SQW + i] = sq_w[(oc * 64 + c) * 9 + q];
}

// ---------------- square 3x3/s2 conv: 32 oc/thread, one out row per block ----------------
__global__ __launch_bounds__(192) void k_sq(const float* __restrict__ x,
                                            const float* __restrict__ sq_b,
                                            const float* __restrict__ ws,
                                            float* __restrict__ out) {
    int xo = threadIdx.x;   // 0..191
    int yo = blockIdx.x;    // 0..191
    int n  = blockIdx.y;    // 0..7
    int ocg = blockIdx.z;   // 0..1
    const float* wp = ws + WS_SQW + ocg * 32;
    const float* bptr = sq_b + ocg * 32;
    float acc[32];
#pragma unroll
    for (int j = 0; j < 32; j++) acc[j] = bptr[j];
    const float* xb = x + (size_t)n * 64 * HW_IN;
    int c2 = 2 * xo;
    for (int c = 0; c < 64; c++) {
        const float* xc = xb + (size_t)c * HW_IN;
#pragma unroll
        for (int ky = 0; ky < 3; ky++) {
            int iy = 2 * yo - 1 + ky;    // wave-uniform
            if (iy >= 0) {
                const float* row = xc + (size_t)iy * WIN;
                float2 v12 = *(const float2*)(row + c2);          // cols 2x, 2x+1
                float v0 = (xo > 0) ? row[c2 - 1] : 0.f;          // col 2x-1
                const float* wr = wp + (c * 9 + ky * 3) * 64;     // uniform -> s_load
#pragma unroll
                for (int j = 0; j < 32; j++)
                    acc[j] += v0 * wr[j] + v12.x * wr[64 + j] + v12.y * wr[128 + j];
            }
        }
    }
    size_t ob = (size_t)n * 128 * PLANE + (size_t)yo * WOUT + xo;
#pragma unroll
    for (int j = 0; j < 32; j++) {
        int ci = ocg * 32 + j;                     // concat channel 0..63
        int co = ((ci & 15) << 3) | (ci >> 4);     // channel shuffle g=8
        out[ob + (size_t)co * PLANE] = acc[j];
    }
}

// ---------------- vertical CondConv 3x1 pad(1,0): 32 oc/thread, raw output ----------------
__global__ __launch_bounds__(192) void k_vert(const float* __restrict__ x,
                                              const float* __restrict__ ws,
                                              float* __restrict__ out) {
    int xo = threadIdx.x, yo = blockIdx.x, n = blockIdx.y;
    const float* wn = ws + WS_AGGV + n * 3072;
    float acc[32];
#pragma unroll
    for (int j = 0; j < 32; j++) acc[j] = 0.f;
    const float* xb = x + (size_t)n * 64 * HW_IN;   // channels 0..31
    int c2 = 2 * xo;
    for (int c = 0; c < 32; c++) {
        const float* xc = xb + (size_t)c * HW_IN;
#pragma unroll
        for (int t = 0; t < 3; t++) {
            int iy = 2 * yo - 1 + t;   // wave-uniform
            if (iy >= 0) {
                float v = xc[(size_t)iy * WIN + c2];
                const float* wr = wn + (c * 3 + t) * 32;   // uniform -> s_load
#pragma unroll
                for (int j = 0; j < 32; j++) acc[j] += v * wr[j];
            }
        }
    }
    size_t ob = (size_t)n * 128 * PLANE + (size_t)yo * WOUT + xo;
#pragma unroll
    for (int j = 0; j < 32; j++) {
        int ci = 64 + j;
        int co = ((ci & 15) << 3) | (ci >> 4);
        out[ob + (size_t)co * PLANE] = acc[j];
    }
}

// ---------------- horizontal CondConv 1x3 pad(0,1): 32 oc/thread, raw output --------------
__global__ __launch_bounds__(192) void k_horz(const float* __restrict__ x,
                                              const float* __restrict__ ws,
                                              float* __restrict__ out) {
    int xo = threadIdx.x, yo = blockIdx.x, n = blockIdx.y;
    const float* wn = ws + WS_AGGH + n * 3072;
    float acc[32];
#pragma unroll
    for (int j = 0; j < 32; j++) acc[j] = 0.f;
    const float* xb = x + ((size_t)n * 64 + 32) * HW_IN;   // channels 32..63
    int c2 = 2 * xo;
    for (int c = 0; c < 32; c++) {
        const float* row = xb + (size_t)c * HW_IN + (size_t)(2 * yo) * WIN;
        float2 v12 = *(const float2*)(row + c2);          // cols 2x, 2x+1
        float v0 = (xo > 0) ? row[c2 - 1] : 0.f;          // col 2x-1
        const float* wr = wn + c * 96;                    // uniform -> s_load
#pragma unroll
        for (int j = 0; j < 32; j++)
            acc[j] += v0 * wr[j] + v12.x * wr[32 + j] + v12.y * wr[64 + j];
    }
    size_t ob = (size_t)n * 128 * PLANE + (size_t)yo * WOUT + xo;
#pragma unroll
    for (int j = 0; j < 32; j++) {
        int ci = 96 + j;
        int co = ((ci & 15) << 3) | (ci >> 4);
        out[ob + (size_t)co * PLANE] = acc[j];
    }
}

// ---------------- BN stats over raw conv output (v/h channels of out) ----------------
__global__ __launch_bounds__(256) void k_stats(const float* __restrict__ out,
                                               float* __restrict__ ws) {
    int sch = blockIdx.x;   // 0..63: 0..31 vert oc, 32..63 horz oc
    int n = blockIdx.y;     // 0..7
    int vh = sch >> 5, oc = sch & 31;
    int ci = 64 + sch;
    int co = ((ci & 15) << 3) | (ci >> 4);
    const float4* p = (const float4*)(out + (size_t)(n * 128 + co) * PLANE);
    float s = 0.f, q = 0.f;
    for (int i = threadIdx.x; i < PLANE / 4; i += 256) {
        float4 v = p[i];
        s += (v.x + v.y) + (v.z + v.w);
        q += (v.x * v.x + v.y * v.y) + (v.z * v.z + v.w * v.w);
    }
    __shared__ float rs[256], rq[256];
    rs[threadIdx.x] = s; rq[threadIdx.x] = q;
    __syncthreads();
    for (int off = 128; off > 0; off >>= 1) {
        if ((int)threadIdx.x < off) {
            rs[threadIdx.x] += rs[threadIdx.x + off];
            rq[threadIdx.x] += rq[threadIdx.x + off];
        }
        __syncthreads();
    }
    if (threadIdx.x == 0) {
        atomicAdd(&ws[WS_STATS + vh * 64 + oc], rs[0]);
        atomicAdd(&ws[WS_STATS + vh * 64 + 32 + oc], rq[0]);
    }
}

// ---------------- BN finalize ----------------
__global__ void k_bnfin(const float* __restrict__ gv, const float* __restrict__ bv,
                        const float* __restrict__ gh, const float* __restrict__ bh,
                        float* __restrict__ ws) {
    int t = threadIdx.x;
    if (t >= 64) return;
    int vh = t >> 5;  // 0 = vert, 1 = horz
    int c = t & 31;
    const float* st = ws + WS_STATS + vh * 64;
    float mean = st[c] * (1.0f / CNT_BN);
    float var = st[32 + c] * (1.0f / CNT_BN) - mean * mean;
    float g = vh ? gh[c] : gv[c];
    float b = vh ? bh[c] : bv[c];
    float scale = g * rsqrtf(var + 1e-5f);
    float* bn = ws + WS_BN + vh * 64;
    bn[c] = scale;
    bn[32 + c] = b - mean * scale;
}

// ---------------- BN apply in-place on v/h channels of out ----------------
__global__ __launch_bounds__(256) void k_apply(float* __restrict__ out,
                                               const float* __restrict__ ws) {
    int sch = blockIdx.x;   // 0..63
    int n = blockIdx.y;     // 0..7
    int vh = sch >> 5, oc = sch & 31;
    int ci = 64 + sch;
    int co = ((ci & 15) << 3) | (ci >> 4);
    const float* bn = ws + WS_BN + vh * 64;
    float scale = bn[oc], shift = bn[32 + oc];
    float4* p = (float4*)(out + (size_t)(n * 128 + co) * PLANE);
    for (int i = threadIdx.x; i < PLANE / 4; i += 256) {
        float4 v = p[i];
        v.x = v.x * scale + shift;
        v.y = v.y * scale + shift;
        v.z = v.z * scale + shift;
        v.w = v.w * scale + shift;
        p[i] = v;
    }
}

extern "C" void kernel_launch(void* const* d_in, const int* in_sizes, int n_in,
                              void* d_out, int out_size, void* d_ws, size_t ws_size,
                              hipStream_t stream) {
    const float* x    = (const float*)d_in[0];
    const float* sq_w = (const float*)d_in[1];
    const float* sq_b = (const float*)d_in[2];
    const float* aw_v = (const float*)d_in[3];
    const float* ab_v = (const float*)d_in[4];
    const float* w_v  = (const float*)d_in[5];
    const float* gv   = (const float*)d_in[6];
    const float* bv   = (const float*)d_in[7];
    const float* aw_h = (const float*)d_in[8];
    const float* ab_h = (const float*)d_in[9];
    const float* w_h  = (const float*)d_in[10];
    const float* gh   = (const float*)d_in[11];
    const float* bh   = (const float*)d_in[12];
    float* out = (float*)d_out;
    float* ws = (float*)d_ws;

    hipLaunchKernelGGL(k_zero, dim3(1), dim3(128), 0, stream, ws);
    hipLaunchKernelGGL(k_means, dim3(512), dim3(256), 0, stream, x, ws);
    hipLaunchKernelGGL(k_agg, dim3(8), dim3(256), 0, stream,
                       aw_v, ab_v, w_v, aw_h, ab_h, w_h, ws);
    hipLaunchKernelGGL(k_cvtw, dim3(144), dim3(256), 0, stream, sq_w, ws);
    hipLaunchKernelGGL(k_vert, dim3(192, 8), dim3(192), 0, stream, x, ws, out);
    hipLaunchKernelGGL(k_horz, dim3(192, 8), dim3(192), 0, stream, x, ws, out);
    hipLaunchKernelGGL(k_stats, dim3(64, 8), dim3(256), 0, stream, out, ws);
    hipLaunchKernelGGL(k_bnfin, dim3(1), dim3(64), 0, stream, gv, bv, gh, bh, ws);
    hipLaunchKernelGGL(k_apply, dim3(64, 8), dim3(256), 0, stream, out, ws);
    hipLaunchKernelGGL(k_sq, dim3(192, 8, 2), dim3(192), 0, stream, x, sq_b, ws, out);
}